// Round 6
// baseline (271.715 us; speedup 1.0000x reference)
//
#include <hip/hip_runtime.h>
#include <hip/hip_bf16.h>
#include <cstdint>
#include <cstddef>

typedef __hip_bfloat16 bf16;
typedef short bf16x8 __attribute__((ext_vector_type(8)));
typedef float f32x4 __attribute__((ext_vector_type(4)));
typedef float f32x16 __attribute__((ext_vector_type(16)));
typedef int i32x4 __attribute__((ext_vector_type(4)));

#define MFMA16(a, b, c) __builtin_amdgcn_mfma_f32_16x16x32_bf16((a), (b), (c), 0, 0, 0)
#define MFMA32(a, b, c) __builtin_amdgcn_mfma_f32_32x32x16_bf16((a), (b), (c), 0, 0, 0)

// async global->LDS, 16B per lane. dst must be wave-uniform base; HW adds lane*16.
__device__ __forceinline__ void glds16(const bf16* g, bf16* l)
{
    __builtin_amdgcn_global_load_lds(
        (const __attribute__((address_space(1))) void*)g,
        (__attribute__((address_space(3))) void*)l, 16, 0, 0);
}

__device__ __forceinline__ unsigned pkbf16(float a, float b)
{
    bf16 ba = __float2bfloat16(a), bb = __float2bfloat16(b);
    unsigned ua = *reinterpret_cast<unsigned short*>(&ba);
    unsigned ub = *reinterpret_cast<unsigned short*>(&bb);
    return ua | (ub << 16);
}

// ---------------------------------------------------------------- converts
__global__ void cvt_f32_bf16(const float* __restrict__ in, bf16* __restrict__ out, int n4)
{
    int i = blockIdx.x * blockDim.x + threadIdx.x;
    if (i >= n4) return;
    float4 v = *reinterpret_cast<const float4*>(in + (size_t)i * 4);
    __align__(8) bf16 tmp[4];
    tmp[0] = __float2bfloat16(v.x);
    tmp[1] = __float2bfloat16(v.y);
    tmp[2] = __float2bfloat16(v.z);
    tmp[3] = __float2bfloat16(v.w);
    *reinterpret_cast<short4*>(out + (size_t)i * 4) = *reinterpret_cast<short4*>(tmp);
}

// ---------------------------------------------------------------- rope table
__global__ void rope_table_kernel(float2* __restrict__ tab)
{
    int i = blockIdx.x * blockDim.x + threadIdx.x;   // 65536
    int pos = i >> 5, f = i & 31;
    float inv = powf(10000.f, -(float)f * (1.f / 32.f));
    float ang = (float)pos * inv;
    tab[i] = make_float2(cosf(ang), sinf(ang));
}

// ---------------------------------------------------------------- rope apply (in-place on q,k cols of qkv buffer)
__global__ void rope_apply_kernel(bf16* __restrict__ qkv, const float2* __restrict__ tab)
{
    int idx = blockIdx.x * blockDim.x + threadIdx.x;   // 1,048,576 total; 8 bf16 each
    int row = idx >> 8;
    int cc  = (idx & 255) * 8;
    int pos = row & 2047;
    int hd  = cc & 63;
    bf16* p = qkv + (size_t)row * 3072 + cc;
    i32x4 v = *reinterpret_cast<const i32x4*>(p);
    bf16* e = reinterpret_cast<bf16*>(&v);
    const float2* tb = tab + pos * 32 + (hd >> 1);
#pragma unroll
    for (int pp = 0; pp < 4; ++pp) {
        float2 cs = tb[pp];
        float x1 = __bfloat162float(e[2 * pp]);
        float x2 = __bfloat162float(e[2 * pp + 1]);
        e[2 * pp]     = __float2bfloat16(x1 * cs.x - x2 * cs.y);
        e[2 * pp + 1] = __float2bfloat16(x2 * cs.x + x1 * cs.y);
    }
    *reinterpret_cast<i32x4*>(p) = v;
}

// ---------------------------------------------------------------- GEMM  C[M,N] = A[M,K] @ BT[N,K]^T + bias
__device__ inline void store_out(float* p, float v) { *p = v; }
__device__ inline void store_out(bf16* p, float v) { *p = __float2bfloat16(v); }

template <typename OutT>
__global__ void gemm_bt_kernel(const bf16* __restrict__ A, const bf16* __restrict__ BT,
                               const float* __restrict__ bias, OutT* __restrict__ C,
                               int M, int N, int K)
{
    constexpr int BM = 128, BN = 128, BK = 32;
    __shared__ __align__(16) bf16 Al[BM * BK];      // linear [row][32]
    __shared__ __align__(16) bf16 Bl[BN * BK];

    const int tid = threadIdx.x;
    const int l = tid & 63;
    const int w = tid >> 6;
    const int wr = w >> 1, wc = w & 1;              // 2x2 wave grid, 64x64 per wave
    const int l15 = l & 15, lhi = l >> 4;
    const int row0 = blockIdx.x * BM, col0 = blockIdx.y * BN;

    const int ar0 = tid >> 2, ar1 = (tid + 256) >> 2;
    const int ac  = (tid & 3) * 8;
    const bf16* Ag0 = A + (size_t)(row0 + ar0) * K + ac;
    const bf16* Ag1 = A + (size_t)(row0 + ar1) * K + ac;
    const bf16* Bg0 = BT + (size_t)(col0 + ar0) * K + ac;
    const bf16* Bg1 = BT + (size_t)(col0 + ar1) * K + ac;
    const int wbase = (tid & 192) * 8;              // wave-uniform LDS base (elems)
    bf16* sA0 = &Al[wbase];
    bf16* sA1 = &Al[2048 + wbase];
    bf16* sB0 = &Bl[wbase];
    bf16* sB1 = &Bl[2048 + wbase];

    f32x4 acc[4][4] = {};

    for (int k0 = 0; k0 < K; k0 += BK) {
        __syncthreads();
        glds16(Ag0 + k0, sA0);
        glds16(Ag1 + k0, sA1);
        glds16(Bg0 + k0, sB0);
        glds16(Bg1 + k0, sB1);
        __syncthreads();
        bf16x8 af[4], bfr[4];
#pragma unroll
        for (int m = 0; m < 4; ++m)
            af[m] = *reinterpret_cast<const bf16x8*>(&Al[(wr * 64 + m * 16 + l15) * BK + lhi * 8]);
#pragma unroll
        for (int n = 0; n < 4; ++n)
            bfr[n] = *reinterpret_cast<const bf16x8*>(&Bl[(wc * 64 + n * 16 + l15) * BK + lhi * 8]);
#pragma unroll
        for (int m = 0; m < 4; ++m)
#pragma unroll
            for (int n = 0; n < 4; ++n)
                acc[m][n] = MFMA16(af[m], bfr[n], acc[m][n]);
    }

#pragma unroll
    for (int m = 0; m < 4; ++m) {
#pragma unroll
        for (int n = 0; n < 4; ++n) {
            int col = col0 + wc * 64 + n * 16 + l15;
            float bs = bias[col];
#pragma unroll
            for (int j = 0; j < 4; ++j) {
                int row = row0 + wr * 64 + m * 16 + lhi * 4 + j;
                store_out(&C[(size_t)row * N + col], acc[m][n][j] + bs);
            }
        }
    }
}

// ---------------------------------------------------------------- flash attention (causal)
// Swapped-QK^T 32x32 MFMA structure (m214 design):
//   - 4 warps x 32 q-rows; per warp: D1=mfma(K,Q) -> p[r] = S^T[kv=cr(r)+4*hi][q=lane&31]
//   - softmax per lane (one q-row), only shfl_xor(32) to merge lane-halves
//   - P repack to PV A-operand in-register: 16 bf16-packs + 8 shfl_xor(32)
//   - exp2 domain (0.125*log2e folded into Q); T13 defer-max threshold 8
//   - double-buffered K/Vt LDS (pad 68), one barrier/tile
__global__ __launch_bounds__(256, 2)
void attn_kernel(const bf16* __restrict__ qkv, bf16* __restrict__ outp)
{
    constexpr int LDK = 68, LDV = 68;
    __shared__ __align__(16) bf16 Kl[2][64 * LDK];   // [kv][hd]
    __shared__ __align__(16) bf16 Vt[2][64 * LDV];   // [hd][kv]
    __shared__ float wred[4][32];

    const int bh = blockIdx.x;                       // 32
    const int b = bh >> 4, h = bh & 15;
    const int q0b = (15 - (int)blockIdx.y) * 128;    // LPT: heaviest first
    const int tid = threadIdx.x;
    const int w = tid >> 6, l = tid & 63;
    const int q31 = l & 31, hi = l >> 5;
    const int q0w = q0b + w * 32;
    const int qa = q0w + q31;                        // this lane's q row

    const size_t RS = 3072;
    const bf16* base = qkv + (size_t)b * 2048 * RS;

    // Q fragments (B-operand): Q[d = s*16 + hi*8 + j][q = q31], prescaled 0.125*log2e
    bf16x8 qf[4];
    {
        const bf16* qr = base + (size_t)qa * RS + h * 64 + hi * 8;
#pragma unroll
        for (int s = 0; s < 4; ++s) {
            bf16x8 v = *reinterpret_cast<const bf16x8*>(qr + s * 16);
            bf16* e = reinterpret_cast<bf16*>(&v);
#pragma unroll
            for (int j = 0; j < 8; ++j)
                e[j] = __float2bfloat16(__bfloat162float(e[j]) * 0.18033688f);
            qf[s] = v;
        }
    }

    // staging geometry (same as r5, 4 warps)
    const int kr  = tid >> 3;                        // K rows 0..31 (+32)
    const int kc8 = (tid & 7) * 8;
    const bf16* kp = base + (size_t)kr * RS + 1024 + h * 64 + kc8;
    const bf16* vp = base + (size_t)(w * 16) * RS + 2048 + h * 64 + l;  // V col = lane

    i32x4 ka, kb;
    __align__(16) bf16 vt16[16];

    // prologue: tile 0
    ka = *reinterpret_cast<const i32x4*>(kp);
    kb = *reinterpret_cast<const i32x4*>(kp + 32 * RS);
#pragma unroll
    for (int j = 0; j < 16; ++j) vt16[j] = vp[(size_t)j * RS];
    *reinterpret_cast<i32x4*>(&Kl[0][kr * LDK + kc8])        = ka;
    *reinterpret_cast<i32x4*>(&Kl[0][(kr + 32) * LDK + kc8]) = kb;
    *reinterpret_cast<i32x4*>(&Vt[0][l * LDV + w * 16])      = *reinterpret_cast<const i32x4*>(&vt16[0]);
    *reinterpret_cast<i32x4*>(&Vt[0][l * LDV + w * 16 + 8])  = *reinterpret_cast<const i32x4*>(&vt16[8]);
    __syncthreads();

    float m_run = -1e30f, l_run = 0.f;
    f32x16 o0 = {}, o1 = {};

    const int ntiles = q0b / 64 + 2;
    int cur = 0;
    for (int t = 0; t < ntiles; ++t) {
        const int kv0 = t * 64;
        const bool pf = (t + 1 < ntiles);
        if (pf) {                                    // issue next-tile loads (hide under compute)
            kp += 64 * RS;
            vp += 64 * RS;
            ka = *reinterpret_cast<const i32x4*>(kp);
            kb = *reinterpret_cast<const i32x4*>(kp + 32 * RS);
#pragma unroll
            for (int j = 0; j < 16; ++j) vt16[j] = vp[(size_t)j * RS];
        }

        if (kv0 <= q0w + 31) {                       // warp has unmasked work in this tile
            const bf16* Kc = &Kl[cur][0];
            const bf16* Vc = &Vt[cur][0];

            // S^T = K @ Q : p0 = kv rows 0..31 (+4*hi offsets), p1 = rows 32..63
            f32x16 p0 = {}, p1 = {};
#pragma unroll
            for (int s = 0; s < 4; ++s) {
                bf16x8 kf0 = *reinterpret_cast<const bf16x8*>(&Kc[q31 * LDK + s * 16 + hi * 8]);
                bf16x8 kf1 = *reinterpret_cast<const bf16x8*>(&Kc[(32 + q31) * LDK + s * 16 + hi * 8]);
                p0 = MFMA32(kf0, qf[s], p0);
                p1 = MFMA32(kf1, qf[s], p1);
            }

            // causal mask: p[r] has kv = kv0 + cr(r) + 4*hi, cr(r)=(r&3)+8*(r>>2)
            if (kv0 + 63 > q0w) {
                const int lim = qa - kv0 - 4 * hi;
#pragma unroll
                for (int r = 0; r < 16; ++r) {
                    const int cr = (r & 3) + 8 * (r >> 2);
                    if (cr > lim)      p0[r] = -1e30f;
                    if (cr + 32 > lim) p1[r] = -1e30f;
                }
            }

            // row max (lane owns one q-row; merge halves with one shfl)
            float rm = p0[0];
#pragma unroll
            for (int r = 1; r < 16; ++r) rm = fmaxf(rm, p0[r]);
#pragma unroll
            for (int r = 0; r < 16; ++r) rm = fmaxf(rm, p1[r]);
            rm = fmaxf(rm, __shfl_xor(rm, 32));

            // T13 defer-max: rescale only when max grew by >8 (exp2 domain)
            if (!__all(rm - m_run <= 8.0f)) {
                float mnew = fmaxf(m_run, rm);
                float alpha = exp2f(m_run - mnew);
                m_run = mnew;
                l_run *= alpha;
                if (hi == 0) wred[w][q31] = alpha;
#pragma unroll
                for (int g = 0; g < 4; ++g) {
                    f32x4 av = *reinterpret_cast<const f32x4*>(&wred[w][8 * g + 4 * hi]);
#pragma unroll
                    for (int tt = 0; tt < 4; ++tt) {
                        o0[4 * g + tt] *= av[tt];
                        o1[4 * g + tt] *= av[tt];
                    }
                }
            }

            // exp + row sum
            float rsum = 0.f;
#pragma unroll
            for (int r = 0; r < 16; ++r) { p0[r] = exp2f(p0[r] - m_run); rsum += p0[r]; }
#pragma unroll
            for (int r = 0; r < 16; ++r) { p1[r] = exp2f(p1[r] - m_run); rsum += p1[r]; }
            rsum += __shfl_xor(rsum, 32);
            l_run += rsum;

            // pack P to bf16 pairs per kv-octet: A[m]=(kv 8m+4hi+0,1), Bv[m]=(+2,+3)
            unsigned A[8], Bv[8];
#pragma unroll
            for (int m = 0; m < 4; ++m) {
                A[m]      = pkbf16(p0[4 * m],     p0[4 * m + 1]);
                Bv[m]     = pkbf16(p0[4 * m + 2], p0[4 * m + 3]);
                A[m + 4]  = pkbf16(p1[4 * m],     p1[4 * m + 1]);
                Bv[m + 4] = pkbf16(p1[4 * m + 2], p1[4 * m + 3]);
            }

            // PV: pa[ks] covers kv = 16ks+8hi+0..7; missing half from partner lane (xor 32)
#pragma unroll
            for (int ks = 0; ks < 4; ++ks) {
                unsigned sa = hi ? A[2 * ks]  : A[2 * ks + 1];
                unsigned sb = hi ? Bv[2 * ks] : Bv[2 * ks + 1];
                unsigned ra = (unsigned)__shfl_xor((int)sa, 32);
                unsigned rb = (unsigned)__shfl_xor((int)sb, 32);
                union { unsigned u[4]; bf16x8 v; } pa;
                if (hi == 0) { pa.u[0] = A[2 * ks];  pa.u[1] = Bv[2 * ks];  pa.u[2] = ra; pa.u[3] = rb; }
                else         { pa.u[0] = ra; pa.u[1] = rb; pa.u[2] = A[2 * ks + 1]; pa.u[3] = Bv[2 * ks + 1]; }
                bf16x8 vf0 = *reinterpret_cast<const bf16x8*>(&Vc[q31 * LDV + ks * 16 + hi * 8]);
                bf16x8 vf1 = *reinterpret_cast<const bf16x8*>(&Vc[(32 + q31) * LDV + ks * 16 + hi * 8]);
                o0 = MFMA32(pa.v, vf0, o0);
                o1 = MFMA32(pa.v, vf1, o1);
            }
        }

        if (pf) {                                    // write next buffer, single barrier
            const int nxt = cur ^ 1;
            *reinterpret_cast<i32x4*>(&Kl[nxt][kr * LDK + kc8])        = ka;
            *reinterpret_cast<i32x4*>(&Kl[nxt][(kr + 32) * LDK + kc8]) = kb;
            *reinterpret_cast<i32x4*>(&Vt[nxt][l * LDV + w * 16])      = *reinterpret_cast<const i32x4*>(&vt16[0]);
            *reinterpret_cast<i32x4*>(&Vt[nxt][l * LDV + w * 16 + 8])  = *reinterpret_cast<const i32x4*>(&vt16[8]);
            __syncthreads();
            cur = nxt;
        }
    }

    // epilogue: O[q = q0w + cr(r)+4hi][d = q31 (+32)] * (1/l[q])
    if (hi == 0) wred[w][q31] = 1.0f / l_run;
#pragma unroll
    for (int g = 0; g < 4; ++g) {
        f32x4 iv = *reinterpret_cast<const f32x4*>(&wred[w][8 * g + 4 * hi]);
#pragma unroll
        for (int tt = 0; tt < 4; ++tt) {
            const int r = 4 * g + tt;
            const int qrow = q0w + 8 * g + 4 * hi + tt;
            bf16* op = outp + (size_t)(b * 2048 + qrow) * 1024 + h * 64 + q31;
            op[0]  = __float2bfloat16(o0[r] * iv[tt]);
            op[32] = __float2bfloat16(o1[r] * iv[tt]);
        }
    }
}

// ---------------------------------------------------------------- launch
extern "C" void kernel_launch(void* const* d_in, const int* in_sizes, int n_in,
                              void* d_out, int out_size, void* d_ws, size_t ws_size,
                              hipStream_t stream)
{
    const float* x      = (const float*)d_in[0];
    const float* qkv_w  = (const float*)d_in[1];
    const float* qkv_b  = (const float*)d_in[2];
    const float* proj_w = (const float*)d_in[3];
    const float* proj_b = (const float*)d_in[4];
    float* out = (float*)d_out;

    char* ws = (char*)d_ws;
    bf16* x_bf   = (bf16*)ws;  ws += (size_t)4096 * 1024 * 2;
    bf16* wq_bf  = (bf16*)ws;  ws += (size_t)3072 * 1024 * 2;
    bf16* wp_bf  = (bf16*)ws;  ws += (size_t)1024 * 1024 * 2;
    bf16* qkvbuf = (bf16*)ws;  ws += (size_t)4096 * 3072 * 2;
    bf16* aout   = (bf16*)ws;  ws += (size_t)4096 * 1024 * 2;
    float2* tab  = (float2*)ws;

    cvt_f32_bf16<<<4096, 256, 0, stream>>>(x, x_bf, 1048576);
    cvt_f32_bf16<<<3072, 256, 0, stream>>>(qkv_w, wq_bf, 786432);
    cvt_f32_bf16<<<1024, 256, 0, stream>>>(proj_w, wp_bf, 262144);
    rope_table_kernel<<<256, 256, 0, stream>>>(tab);

    // qkv = x @ qkv_w.T + qkv_b   [4096, 3072] bf16
    gemm_bt_kernel<bf16><<<dim3(32, 24), 256, 0, stream>>>(x_bf, wq_bf, qkv_b, qkvbuf, 4096, 3072, 1024);
    // RoPE in place on q,k sections
    rope_apply_kernel<<<4096, 256, 0, stream>>>(qkvbuf, tab);
    // causal flash attention -> aout [4096, 1024] bf16
    attn_kernel<<<dim3(32, 16), 256, 0, stream>>>(qkvbuf, aout);
    // out = aout @ proj_w.T + proj_b  (fp32)
    gemm_bt_kernel<float><<<dim3(32, 8), 256, 0, stream>>>(aout, wp_bf, proj_b, out, 4096, 1024, 1024);
}

// Round 7
// 267.989 us; speedup vs baseline: 1.0139x; 1.0139x over previous
//
#include <hip/hip_runtime.h>
#include <hip/hip_bf16.h>
#include <cstdint>
#include <cstddef>

typedef __hip_bfloat16 bf16;
typedef short bf16x8 __attribute__((ext_vector_type(8)));
typedef float f32x4 __attribute__((ext_vector_type(4)));
typedef float f32x16 __attribute__((ext_vector_type(16)));
typedef int i32x4 __attribute__((ext_vector_type(4)));

#define MFMA16(a, b, c) __builtin_amdgcn_mfma_f32_16x16x32_bf16((a), (b), (c), 0, 0, 0)
#define MFMA32(a, b, c) __builtin_amdgcn_mfma_f32_32x32x16_bf16((a), (b), (c), 0, 0, 0)

// async global->LDS, 16B per lane. dst must be wave-uniform base; HW adds lane*16.
__device__ __forceinline__ void glds16(const bf16* g, bf16* l)
{
    __builtin_amdgcn_global_load_lds(
        (const __attribute__((address_space(1))) void*)g,
        (__attribute__((address_space(3))) void*)l, 16, 0, 0);
}

__device__ __forceinline__ unsigned pkbf16(float a, float b)
{
    bf16 ba = __float2bfloat16(a), bb = __float2bfloat16(b);
    unsigned ua = *reinterpret_cast<unsigned short*>(&ba);
    unsigned ub = *reinterpret_cast<unsigned short*>(&bb);
    return ua | (ub << 16);
}

// ---------------------------------------------------------------- converts
__global__ void cvt_f32_bf16(const float* __restrict__ in, bf16* __restrict__ out, int n4)
{
    int i = blockIdx.x * blockDim.x + threadIdx.x;
    if (i >= n4) return;
    float4 v = *reinterpret_cast<const float4*>(in + (size_t)i * 4);
    __align__(8) bf16 tmp[4];
    tmp[0] = __float2bfloat16(v.x);
    tmp[1] = __float2bfloat16(v.y);
    tmp[2] = __float2bfloat16(v.z);
    tmp[3] = __float2bfloat16(v.w);
    *reinterpret_cast<short4*>(out + (size_t)i * 4) = *reinterpret_cast<short4*>(tmp);
}

// ---------------------------------------------------------------- rope table
__global__ void rope_table_kernel(float2* __restrict__ tab)
{
    int i = blockIdx.x * blockDim.x + threadIdx.x;   // 65536
    int pos = i >> 5, f = i & 31;
    float inv = powf(10000.f, -(float)f * (1.f / 32.f));
    float ang = (float)pos * inv;
    tab[i] = make_float2(cosf(ang), sinf(ang));
}

// ---------------------------------------------------------------- rope apply (in-place on q,k cols of qkv buffer)
__global__ void rope_apply_kernel(bf16* __restrict__ qkv, const float2* __restrict__ tab)
{
    int idx = blockIdx.x * blockDim.x + threadIdx.x;   // 1,048,576 total; 8 bf16 each
    int row = idx >> 8;
    int cc  = (idx & 255) * 8;
    int pos = row & 2047;
    int hd  = cc & 63;
    bf16* p = qkv + (size_t)row * 3072 + cc;
    i32x4 v = *reinterpret_cast<const i32x4*>(p);
    bf16* e = reinterpret_cast<bf16*>(&v);
    const float2* tb = tab + pos * 32 + (hd >> 1);
#pragma unroll
    for (int pp = 0; pp < 4; ++pp) {
        float2 cs = tb[pp];
        float x1 = __bfloat162float(e[2 * pp]);
        float x2 = __bfloat162float(e[2 * pp + 1]);
        e[2 * pp]     = __float2bfloat16(x1 * cs.x - x2 * cs.y);
        e[2 * pp + 1] = __float2bfloat16(x2 * cs.x + x1 * cs.y);
    }
    *reinterpret_cast<i32x4*>(p) = v;
}

// ---------------------------------------------------------------- GEMM  C[M,N] = A[M,K] @ BT[N,K]^T + bias
__device__ inline void store_out(float* p, float v) { *p = v; }
__device__ inline void store_out(bf16* p, float v) { *p = __float2bfloat16(v); }

template <typename OutT>
__global__ void gemm_bt_kernel(const bf16* __restrict__ A, const bf16* __restrict__ BT,
                               const float* __restrict__ bias, OutT* __restrict__ C,
                               int M, int N, int K)
{
    constexpr int BM = 128, BN = 128, BK = 32;
    __shared__ __align__(16) bf16 Al[BM * BK];      // linear [row][32]
    __shared__ __align__(16) bf16 Bl[BN * BK];

    const int tid = threadIdx.x;
    const int l = tid & 63;
    const int w = tid >> 6;
    const int wr = w >> 1, wc = w & 1;              // 2x2 wave grid, 64x64 per wave
    const int l15 = l & 15, lhi = l >> 4;
    const int row0 = blockIdx.x * BM, col0 = blockIdx.y * BN;

    const int ar0 = tid >> 2, ar1 = (tid + 256) >> 2;
    const int ac  = (tid & 3) * 8;
    const bf16* Ag0 = A + (size_t)(row0 + ar0) * K + ac;
    const bf16* Ag1 = A + (size_t)(row0 + ar1) * K + ac;
    const bf16* Bg0 = BT + (size_t)(col0 + ar0) * K + ac;
    const bf16* Bg1 = BT + (size_t)(col0 + ar1) * K + ac;
    const int wbase = (tid & 192) * 8;              // wave-uniform LDS base (elems)
    bf16* sA0 = &Al[wbase];
    bf16* sA1 = &Al[2048 + wbase];
    bf16* sB0 = &Bl[wbase];
    bf16* sB1 = &Bl[2048 + wbase];

    f32x4 acc[4][4] = {};

    for (int k0 = 0; k0 < K; k0 += BK) {
        __syncthreads();
        glds16(Ag0 + k0, sA0);
        glds16(Ag1 + k0, sA1);
        glds16(Bg0 + k0, sB0);
        glds16(Bg1 + k0, sB1);
        __syncthreads();
        bf16x8 af[4], bfr[4];
#pragma unroll
        for (int m = 0; m < 4; ++m)
            af[m] = *reinterpret_cast<const bf16x8*>(&Al[(wr * 64 + m * 16 + l15) * BK + lhi * 8]);
#pragma unroll
        for (int n = 0; n < 4; ++n)
            bfr[n] = *reinterpret_cast<const bf16x8*>(&Bl[(wc * 64 + n * 16 + l15) * BK + lhi * 8]);
#pragma unroll
        for (int m = 0; m < 4; ++m)
#pragma unroll
            for (int n = 0; n < 4; ++n)
                acc[m][n] = MFMA16(af[m], bfr[n], acc[m][n]);
    }

#pragma unroll
    for (int m = 0; m < 4; ++m) {
#pragma unroll
        for (int n = 0; n < 4; ++n) {
            int col = col0 + wc * 64 + n * 16 + l15;
            float bs = bias[col];
#pragma unroll
            for (int j = 0; j < 4; ++j) {
                int row = row0 + wr * 64 + m * 16 + lhi * 4 + j;
                store_out(&C[(size_t)row * N + col], acc[m][n][j] + bs);
            }
        }
    }
}

// ---------------------------------------------------------------- flash attention (causal)
// Swapped-QK^T 32x32 MFMA structure (r6-verified math), regeometried:
//   QBLK=64, 2 warps x 32 q-rows, grid 32 x 32 = 1024 blocks (4 blocks/CU).
//   Per warp: mfma(K,Q) -> lane owns one q-row's 32 P-values in-register;
//   softmax = in-lane reduce + one shfl_xor(32); P repack in-register;
//   exp2 domain; T13 defer-max; double-buffered K/Vt, one barrier/tile.
__global__ __launch_bounds__(128, 2)
void attn_kernel(const bf16* __restrict__ qkv, bf16* __restrict__ outp)
{
    constexpr int LDK = 68, LDV = 68;
    __shared__ __align__(16) bf16 Kl[2][64 * LDK];   // [kv][hd]
    __shared__ __align__(16) bf16 Vt[2][64 * LDV];   // [hd][kv]
    __shared__ float wred[2][32];

    const int bh = blockIdx.x;                       // 32
    const int b = bh >> 4, h = bh & 15;
    const int q0b = (31 - (int)blockIdx.y) * 64;     // LPT: heaviest first
    const int tid = threadIdx.x;                     // 128
    const int w = tid >> 6, l = tid & 63;
    const int q31 = l & 31, hi = l >> 5;
    const int q0w = q0b + w * 32;
    const int qa = q0w + q31;                        // this lane's q row

    const size_t RS = 3072;
    const bf16* base = qkv + (size_t)b * 2048 * RS;

    // Q fragments (B-operand): Q[d = s*16 + hi*8 + j][q = q31], prescaled 0.125*log2e
    bf16x8 qf[4];
    {
        const bf16* qr = base + (size_t)qa * RS + h * 64 + hi * 8;
#pragma unroll
        for (int s = 0; s < 4; ++s) {
            bf16x8 v = *reinterpret_cast<const bf16x8*>(qr + s * 16);
            bf16* e = reinterpret_cast<bf16*>(&v);
#pragma unroll
            for (int j = 0; j < 8; ++j)
                e[j] = __float2bfloat16(__bfloat162float(e[j]) * 0.18033688f);
            qf[s] = v;
        }
    }

    // staging geometry (128 threads)
    const int kr  = tid >> 2;                        // K rows 0..31 (+32 for 2nd pair)
    const int kc  = (tid & 3) * 16;                  // 16-elem (32B) column chunk
    const bf16* kp = base + (size_t)kr * RS + 1024 + h * 64 + kc;
    const bf16* vp = base + (size_t)(w * 32) * RS + 2048 + h * 64 + l;  // V col = lane

    i32x4 ka0, ka1, ka2, ka3;
    __align__(16) bf16 vt32[32];

    // prologue: tile 0
    ka0 = *reinterpret_cast<const i32x4*>(kp);
    ka1 = *reinterpret_cast<const i32x4*>(kp + 8);
    ka2 = *reinterpret_cast<const i32x4*>(kp + 32 * RS);
    ka3 = *reinterpret_cast<const i32x4*>(kp + 32 * RS + 8);
#pragma unroll
    for (int j = 0; j < 32; ++j) vt32[j] = vp[(size_t)j * RS];
    *reinterpret_cast<i32x4*>(&Kl[0][kr * LDK + kc])            = ka0;
    *reinterpret_cast<i32x4*>(&Kl[0][kr * LDK + kc + 8])        = ka1;
    *reinterpret_cast<i32x4*>(&Kl[0][(kr + 32) * LDK + kc])     = ka2;
    *reinterpret_cast<i32x4*>(&Kl[0][(kr + 32) * LDK + kc + 8]) = ka3;
#pragma unroll
    for (int c = 0; c < 4; ++c)
        *reinterpret_cast<i32x4*>(&Vt[0][l * LDV + w * 32 + c * 8]) =
            *reinterpret_cast<const i32x4*>(&vt32[c * 8]);
    __syncthreads();

    float m_run = -1e30f, l_run = 0.f;
    f32x16 o0 = {}, o1 = {};

    const int ntiles = q0b / 64 + 1;
    int cur = 0;
    for (int t = 0; t < ntiles; ++t) {
        const int kv0 = t * 64;
        const bool pf = (t + 1 < ntiles);
        if (pf) {                                    // issue next-tile loads (hide under compute)
            kp += 64 * RS;
            vp += 64 * RS;
            ka0 = *reinterpret_cast<const i32x4*>(kp);
            ka1 = *reinterpret_cast<const i32x4*>(kp + 8);
            ka2 = *reinterpret_cast<const i32x4*>(kp + 32 * RS);
            ka3 = *reinterpret_cast<const i32x4*>(kp + 32 * RS + 8);
#pragma unroll
            for (int j = 0; j < 32; ++j) vt32[j] = vp[(size_t)j * RS];
        }

        if (kv0 <= q0w + 31) {                       // warp has unmasked work in this tile
            const bf16* Kc = &Kl[cur][0];
            const bf16* Vc = &Vt[cur][0];

            // S^T = K @ Q : p0 = kv rows 0..31 (+4*hi offsets), p1 = rows 32..63
            f32x16 p0 = {}, p1 = {};
#pragma unroll
            for (int s = 0; s < 4; ++s) {
                bf16x8 kf0 = *reinterpret_cast<const bf16x8*>(&Kc[q31 * LDK + s * 16 + hi * 8]);
                bf16x8 kf1 = *reinterpret_cast<const bf16x8*>(&Kc[(32 + q31) * LDK + s * 16 + hi * 8]);
                p0 = MFMA32(kf0, qf[s], p0);
                p1 = MFMA32(kf1, qf[s], p1);
            }

            // causal mask: p[r] has kv = kv0 + cr(r) + 4*hi, cr(r)=(r&3)+8*(r>>2)
            if (kv0 + 63 > q0w) {
                const int lim = qa - kv0 - 4 * hi;
#pragma unroll
                for (int r = 0; r < 16; ++r) {
                    const int cr = (r & 3) + 8 * (r >> 2);
                    if (cr > lim)      p0[r] = -1e30f;
                    if (cr + 32 > lim) p1[r] = -1e30f;
                }
            }

            // row max (lane owns one q-row; merge halves with one shfl)
            float rm = p0[0];
#pragma unroll
            for (int r = 1; r < 16; ++r) rm = fmaxf(rm, p0[r]);
#pragma unroll
            for (int r = 0; r < 16; ++r) rm = fmaxf(rm, p1[r]);
            rm = fmaxf(rm, __shfl_xor(rm, 32));

            // T13 defer-max: rescale only when max grew by >8 (exp2 domain)
            if (!__all(rm - m_run <= 8.0f)) {
                float mnew = fmaxf(m_run, rm);
                float alpha = exp2f(m_run - mnew);
                m_run = mnew;
                l_run *= alpha;
                if (hi == 0) wred[w][q31] = alpha;
#pragma unroll
                for (int g = 0; g < 4; ++g) {
                    f32x4 av = *reinterpret_cast<const f32x4*>(&wred[w][8 * g + 4 * hi]);
#pragma unroll
                    for (int tt = 0; tt < 4; ++tt) {
                        o0[4 * g + tt] *= av[tt];
                        o1[4 * g + tt] *= av[tt];
                    }
                }
            }

            // exp + row sum
            float rsum = 0.f;
#pragma unroll
            for (int r = 0; r < 16; ++r) { p0[r] = exp2f(p0[r] - m_run); rsum += p0[r]; }
#pragma unroll
            for (int r = 0; r < 16; ++r) { p1[r] = exp2f(p1[r] - m_run); rsum += p1[r]; }
            rsum += __shfl_xor(rsum, 32);
            l_run += rsum;

            // pack P to bf16 pairs per kv-octet: A[m]=(kv 8m+4hi+0,1), Bv[m]=(+2,+3)
            unsigned A[8], Bv[8];
#pragma unroll
            for (int m = 0; m < 4; ++m) {
                A[m]      = pkbf16(p0[4 * m],     p0[4 * m + 1]);
                Bv[m]     = pkbf16(p0[4 * m + 2], p0[4 * m + 3]);
                A[m + 4]  = pkbf16(p1[4 * m],     p1[4 * m + 1]);
                Bv[m + 4] = pkbf16(p1[4 * m + 2], p1[4 * m + 3]);
            }

            // PV: pa[ks] covers kv = 16ks+8hi+0..7; missing half from partner lane (xor 32)
#pragma unroll
            for (int ks = 0; ks < 4; ++ks) {
                unsigned sa = hi ? A[2 * ks]  : A[2 * ks + 1];
                unsigned sb = hi ? Bv[2 * ks] : Bv[2 * ks + 1];
                unsigned ra = (unsigned)__shfl_xor((int)sa, 32);
                unsigned rb = (unsigned)__shfl_xor((int)sb, 32);
                union { unsigned u[4]; bf16x8 v; } pa;
                if (hi == 0) { pa.u[0] = A[2 * ks];  pa.u[1] = Bv[2 * ks];  pa.u[2] = ra; pa.u[3] = rb; }
                else         { pa.u[0] = ra; pa.u[1] = rb; pa.u[2] = A[2 * ks + 1]; pa.u[3] = Bv[2 * ks + 1]; }
                bf16x8 vf0 = *reinterpret_cast<const bf16x8*>(&Vc[q31 * LDV + ks * 16 + hi * 8]);
                bf16x8 vf1 = *reinterpret_cast<const bf16x8*>(&Vc[(32 + q31) * LDV + ks * 16 + hi * 8]);
                o0 = MFMA32(pa.v, vf0, o0);
                o1 = MFMA32(pa.v, vf1, o1);
            }
        }

        if (pf) {                                    // write next buffer, single barrier
            const int nxt = cur ^ 1;
            *reinterpret_cast<i32x4*>(&Kl[nxt][kr * LDK + kc])            = ka0;
            *reinterpret_cast<i32x4*>(&Kl[nxt][kr * LDK + kc + 8])        = ka1;
            *reinterpret_cast<i32x4*>(&Kl[nxt][(kr + 32) * LDK + kc])     = ka2;
            *reinterpret_cast<i32x4*>(&Kl[nxt][(kr + 32) * LDK + kc + 8]) = ka3;
#pragma unroll
            for (int c = 0; c < 4; ++c)
                *reinterpret_cast<i32x4*>(&Vt[nxt][l * LDV + w * 32 + c * 8]) =
                    *reinterpret_cast<const i32x4*>(&vt32[c * 8]);
            __syncthreads();
            cur = nxt;
        }
    }

    // epilogue: O[q = q0w + cr(r)+4hi][d = q31 (+32)] * (1/l[q])
    if (hi == 0) wred[w][q31] = 1.0f / l_run;
#pragma unroll
    for (int g = 0; g < 4; ++g) {
        f32x4 iv = *reinterpret_cast<const f32x4*>(&wred[w][8 * g + 4 * hi]);
#pragma unroll
        for (int tt = 0; tt < 4; ++tt) {
            const int r = 4 * g + tt;
            const int qrow = q0w + 8 * g + 4 * hi + tt;
            bf16* op = outp + (size_t)(b * 2048 + qrow) * 1024 + h * 64 + q31;
            op[0]  = __float2bfloat16(o0[r] * iv[tt]);
            op[32] = __float2bfloat16(o1[r] * iv[tt]);
        }
    }
}

// ---------------------------------------------------------------- launch
extern "C" void kernel_launch(void* const* d_in, const int* in_sizes, int n_in,
                              void* d_out, int out_size, void* d_ws, size_t ws_size,
                              hipStream_t stream)
{
    const float* x      = (const float*)d_in[0];
    const float* qkv_w  = (const float*)d_in[1];
    const float* qkv_b  = (const float*)d_in[2];
    const float* proj_w = (const float*)d_in[3];
    const float* proj_b = (const float*)d_in[4];
    float* out = (float*)d_out;

    char* ws = (char*)d_ws;
    bf16* x_bf   = (bf16*)ws;  ws += (size_t)4096 * 1024 * 2;
    bf16* wq_bf  = (bf16*)ws;  ws += (size_t)3072 * 1024 * 2;
    bf16* wp_bf  = (bf16*)ws;  ws += (size_t)1024 * 1024 * 2;
    bf16* qkvbuf = (bf16*)ws;  ws += (size_t)4096 * 3072 * 2;
    bf16* aout   = (bf16*)ws;  ws += (size_t)4096 * 1024 * 2;
    float2* tab  = (float2*)ws;

    cvt_f32_bf16<<<4096, 256, 0, stream>>>(x, x_bf, 1048576);
    cvt_f32_bf16<<<3072, 256, 0, stream>>>(qkv_w, wq_bf, 786432);
    cvt_f32_bf16<<<1024, 256, 0, stream>>>(proj_w, wp_bf, 262144);
    rope_table_kernel<<<256, 256, 0, stream>>>(tab);

    // qkv = x @ qkv_w.T + qkv_b   [4096, 3072] bf16
    gemm_bt_kernel<bf16><<<dim3(32, 24), 256, 0, stream>>>(x_bf, wq_bf, qkv_b, qkvbuf, 4096, 3072, 1024);
    // RoPE in place on q,k sections
    rope_apply_kernel<<<4096, 256, 0, stream>>>(qkvbuf, tab);
    // causal flash attention -> aout [4096, 1024] bf16
    attn_kernel<<<dim3(32, 32), 128, 0, stream>>>(qkvbuf, aout);
    // out = aout @ proj_w.T + proj_b  (fp32)
    gemm_bt_kernel<float><<<dim3(32, 8), 256, 0, stream>>>(aout, wp_bf, proj_b, out, 4096, 1024, 1024);
}

// Round 9
// 250.406 us; speedup vs baseline: 1.0851x; 1.0702x over previous
//
#include <hip/hip_runtime.h>
#include <hip/hip_bf16.h>
#include <cstdint>
#include <cstddef>

typedef __hip_bfloat16 bf16;
typedef short bf16x8 __attribute__((ext_vector_type(8)));
typedef float f32x4 __attribute__((ext_vector_type(4)));
typedef float f32x16 __attribute__((ext_vector_type(16)));
typedef int i32x4 __attribute__((ext_vector_type(4)));

#define MFMA16(a, b, c) __builtin_amdgcn_mfma_f32_16x16x32_bf16((a), (b), (c), 0, 0, 0)
#define MFMA32(a, b, c) __builtin_amdgcn_mfma_f32_32x32x16_bf16((a), (b), (c), 0, 0, 0)

// async global->LDS, 16B per lane. dst must be wave-uniform base; HW adds lane*16.
__device__ __forceinline__ void glds16(const bf16* g, bf16* l)
{
    __builtin_amdgcn_global_load_lds(
        (const __attribute__((address_space(1))) void*)g,
        (__attribute__((address_space(3))) void*)l, 16, 0, 0);
}

__device__ __forceinline__ unsigned pkbf16(float a, float b)
{
    bf16 ba = __float2bfloat16(a), bb = __float2bfloat16(b);
    unsigned ua = *reinterpret_cast<unsigned short*>(&ba);
    unsigned ub = *reinterpret_cast<unsigned short*>(&bb);
    return ua | (ub << 16);
}

// ---------------------------------------------------------------- converts
__global__ void cvt_f32_bf16(const float* __restrict__ in, bf16* __restrict__ out, int n4)
{
    int i = blockIdx.x * blockDim.x + threadIdx.x;
    if (i >= n4) return;
    float4 v = *reinterpret_cast<const float4*>(in + (size_t)i * 4);
    __align__(8) bf16 tmp[4];
    tmp[0] = __float2bfloat16(v.x);
    tmp[1] = __float2bfloat16(v.y);
    tmp[2] = __float2bfloat16(v.z);
    tmp[3] = __float2bfloat16(v.w);
    *reinterpret_cast<short4*>(out + (size_t)i * 4) = *reinterpret_cast<short4*>(tmp);
}

// ---------------------------------------------------------------- rope table
__global__ void rope_table_kernel(float2* __restrict__ tab)
{
    int i = blockIdx.x * blockDim.x + threadIdx.x;   // 65536
    int pos = i >> 5, f = i & 31;
    float inv = powf(10000.f, -(float)f * (1.f / 32.f));
    float ang = (float)pos * inv;
    tab[i] = make_float2(cosf(ang), sinf(ang));
}

// ---------------------------------------------------------------- rope apply
__global__ void rope_apply_kernel(bf16* __restrict__ qkv, const float2* __restrict__ tab)
{
    int idx = blockIdx.x * blockDim.x + threadIdx.x;   // 1,048,576 total; 8 bf16 each
    int row = idx >> 8;
    int cc  = (idx & 255) * 8;
    int pos = row & 2047;
    int hd  = cc & 63;
    bf16* p = qkv + (size_t)row * 3072 + cc;
    i32x4 v = *reinterpret_cast<const i32x4*>(p);
    bf16* e = reinterpret_cast<bf16*>(&v);
    const float2* tb = tab + pos * 32 + (hd >> 1);
#pragma unroll
    for (int pp = 0; pp < 4; ++pp) {
        float2 cs = tb[pp];
        float x1 = __bfloat162float(e[2 * pp]);
        float x2 = __bfloat162float(e[2 * pp + 1]);
        e[2 * pp]     = __float2bfloat16(x1 * cs.x - x2 * cs.y);
        e[2 * pp + 1] = __float2bfloat16(x2 * cs.x + x1 * cs.y);
    }
    *reinterpret_cast<i32x4*>(p) = v;
}

// ---------------------------------------------------------------- V transpose: qkv V-section -> vt[bh][d][n]
__global__ void transpose_v_kernel(const bf16* __restrict__ qkv, bf16* __restrict__ vt)
{
    __shared__ __align__(16) bf16 Tl[64 * 68];
    const int bid = blockIdx.x;              // 1024 = 32 bh * 32 n-tiles
    const int bh = bid >> 5, nt = bid & 31;
    const int b = bh >> 4, h = bh & 15;
    const int n0 = nt * 64;
    const int tid = threadIdx.x;             // 256
#pragma unroll
    for (int cc = 0; cc < 2; ++cc) {
        int c = tid + cc * 256;
        int r = c >> 3, d8 = (c & 7) * 8;
        i32x4 v = *reinterpret_cast<const i32x4*>(
            qkv + (size_t)(b * 2048 + n0 + r) * 3072 + 2048 + h * 64 + d8);
        *reinterpret_cast<i32x4*>(&Tl[r * 68 + d8]) = v;
    }
    __syncthreads();
#pragma unroll
    for (int cc = 0; cc < 2; ++cc) {
        int c = tid + cc * 256;
        int d = c >> 3, n8 = (c & 7) * 8;
        __align__(16) bf16 tmp[8];
#pragma unroll
        for (int i = 0; i < 8; ++i) tmp[i] = Tl[(n8 + i) * 68 + d];
        *reinterpret_cast<i32x4*>(vt + ((size_t)bh * 64 + d) * 2048 + n0 + n8) =
            *reinterpret_cast<const i32x4*>(tmp);
    }
}

// ---------------------------------------------------------------- GEMM  C[M,N] = A[M,K] @ BT[N,K]^T + bias
__device__ inline void store_out(float* p, float v) { *p = v; }
__device__ inline void store_out(bf16* p, float v) { *p = __float2bfloat16(v); }

template <typename OutT>
__global__ void gemm_bt_kernel(const bf16* __restrict__ A, const bf16* __restrict__ BT,
                               const float* __restrict__ bias, OutT* __restrict__ C,
                               int M, int N, int K)
{
    constexpr int BM = 128, BN = 128, BK = 32;
    __shared__ __align__(16) bf16 Al[BM * BK];      // linear [row][32]
    __shared__ __align__(16) bf16 Bl[BN * BK];

    const int tid = threadIdx.x;
    const int l = tid & 63;
    const int w = tid >> 6;
    const int wr = w >> 1, wc = w & 1;              // 2x2 wave grid, 64x64 per wave
    const int l15 = l & 15, lhi = l >> 4;
    const int row0 = blockIdx.x * BM, col0 = blockIdx.y * BN;

    const int ar0 = tid >> 2, ar1 = (tid + 256) >> 2;
    const int ac  = (tid & 3) * 8;
    const bf16* Ag0 = A + (size_t)(row0 + ar0) * K + ac;
    const bf16* Ag1 = A + (size_t)(row0 + ar1) * K + ac;
    const bf16* Bg0 = BT + (size_t)(col0 + ar0) * K + ac;
    const bf16* Bg1 = BT + (size_t)(col0 + ar1) * K + ac;
    const int wbase = (tid & 192) * 8;              // wave-uniform LDS base (elems)
    bf16* sA0 = &Al[wbase];
    bf16* sA1 = &Al[2048 + wbase];
    bf16* sB0 = &Bl[wbase];
    bf16* sB1 = &Bl[2048 + wbase];

    f32x4 acc[4][4] = {};

    for (int k0 = 0; k0 < K; k0 += BK) {
        __syncthreads();
        glds16(Ag0 + k0, sA0);
        glds16(Ag1 + k0, sA1);
        glds16(Bg0 + k0, sB0);
        glds16(Bg1 + k0, sB1);
        __syncthreads();
        bf16x8 af[4], bfr[4];
#pragma unroll
        for (int m = 0; m < 4; ++m)
            af[m] = *reinterpret_cast<const bf16x8*>(&Al[(wr * 64 + m * 16 + l15) * BK + lhi * 8]);
#pragma unroll
        for (int n = 0; n < 4; ++n)
            bfr[n] = *reinterpret_cast<const bf16x8*>(&Bl[(wc * 64 + n * 16 + l15) * BK + lhi * 8]);
#pragma unroll
        for (int m = 0; m < 4; ++m)
#pragma unroll
            for (int n = 0; n < 4; ++n)
                acc[m][n] = MFMA16(af[m], bfr[n], acc[m][n]);
    }

#pragma unroll
    for (int m = 0; m < 4; ++m) {
#pragma unroll
        for (int n = 0; n < 4; ++n) {
            int col = col0 + wc * 64 + n * 16 + l15;
            float bs = bias[col];
#pragma unroll
            for (int j = 0; j < 4; ++j) {
                int row = row0 + wr * 64 + m * 16 + lhi * 4 + j;
                store_out(&C[(size_t)row * N + col], acc[m][n][j] + bs);
            }
        }
    }
}

// ---------------------------------------------------------------- flash attention (causal)
// r7 structure (verified): swapped-QK^T 32x32, QBLK=64, 2 warps, dbuf, 1 barrier/tile.
// ONLY change vs r7: V staged from pre-transposed vt[bh][d][n] via 4 coalesced b128
// loads + 4 b128 LDS writes (replaces the 32-scalar-strided global gather).
__global__ __launch_bounds__(128, 2)
void attn_kernel(const bf16* __restrict__ qkv, const bf16* __restrict__ vt,
                 bf16* __restrict__ outp)
{
    constexpr int LDK = 68, LDV = 68;
    __shared__ __align__(16) bf16 Kl[2][64 * LDK];   // [kv][hd]
    __shared__ __align__(16) bf16 Vt[2][64 * LDV];   // [hd][kv]
    __shared__ float wred[2][32];

    const int bh = blockIdx.x;                       // 32
    const int b = bh >> 4, h = bh & 15;
    const int q0b = (31 - (int)blockIdx.y) * 64;     // LPT: heaviest first
    const int tid = threadIdx.x;                     // 128
    const int w = tid >> 6, l = tid & 63;
    const int q31 = l & 31, hi = l >> 5;
    const int q0w = q0b + w * 32;
    const int qa = q0w + q31;

    const size_t RS = 3072;
    const bf16* base = qkv + (size_t)b * 2048 * RS;

    // Q fragments (B-operand): Q[d = s*16 + hi*8 + j][q = q31], prescaled 0.125*log2e
    bf16x8 qf[4];
    {
        const bf16* qr = base + (size_t)qa * RS + h * 64 + hi * 8;
#pragma unroll
        for (int s = 0; s < 4; ++s) {
            bf16x8 v = *reinterpret_cast<const bf16x8*>(qr + s * 16);
            bf16* e = reinterpret_cast<bf16*>(&v);
#pragma unroll
            for (int j = 0; j < 8; ++j)
                e[j] = __float2bfloat16(__bfloat162float(e[j]) * 0.18033688f);
            qf[s] = v;
        }
    }

    // staging geometry (128 threads)
    const int kr  = tid >> 2;                        // K rows 0..31 (+32 for 2nd pair)
    const int kc  = (tid & 3) * 16;                  // 16-elem (32B) column chunk
    const bf16* kp = base + (size_t)kr * RS + 1024 + h * 64 + kc;
    // V from vt[bh][d][n]: thread covers d = (tid>>3)+cc*16, kv chunk (tid&7)*8
    const int vd  = tid >> 3;                        // 0..15
    const int vk8 = (tid & 7) * 8;
    const bf16* vS = vt + ((size_t)bh * 64 + vd) * 2048 + vk8;

    i32x4 ka0, ka1, ka2, ka3;
    i32x4 vv[4];

    // prologue: tile 0
    ka0 = *reinterpret_cast<const i32x4*>(kp);
    ka1 = *reinterpret_cast<const i32x4*>(kp + 8);
    ka2 = *reinterpret_cast<const i32x4*>(kp + 32 * RS);
    ka3 = *reinterpret_cast<const i32x4*>(kp + 32 * RS + 8);
#pragma unroll
    for (int cc = 0; cc < 4; ++cc)
        vv[cc] = *reinterpret_cast<const i32x4*>(vS + (size_t)cc * 16 * 2048);
    *reinterpret_cast<i32x4*>(&Kl[0][kr * LDK + kc])            = ka0;
    *reinterpret_cast<i32x4*>(&Kl[0][kr * LDK + kc + 8])        = ka1;
    *reinterpret_cast<i32x4*>(&Kl[0][(kr + 32) * LDK + kc])     = ka2;
    *reinterpret_cast<i32x4*>(&Kl[0][(kr + 32) * LDK + kc + 8]) = ka3;
#pragma unroll
    for (int cc = 0; cc < 4; ++cc)
        *reinterpret_cast<i32x4*>(&Vt[0][(vd + cc * 16) * LDV + vk8]) = vv[cc];
    __syncthreads();

    float m_run = -1e30f, l_run = 0.f;
    f32x16 o0 = {}, o1 = {};

    const int ntiles = q0b / 64 + 1;
    int cur = 0;
    for (int t = 0; t < ntiles; ++t) {
        const int kv0 = t * 64;
        const bool pf = (t + 1 < ntiles);
        if (pf) {                                    // issue next-tile loads (hide under compute)
            kp += 64 * RS;
            ka0 = *reinterpret_cast<const i32x4*>(kp);
            ka1 = *reinterpret_cast<const i32x4*>(kp + 8);
            ka2 = *reinterpret_cast<const i32x4*>(kp + 32 * RS);
            ka3 = *reinterpret_cast<const i32x4*>(kp + 32 * RS + 8);
#pragma unroll
            for (int cc = 0; cc < 4; ++cc)
                vv[cc] = *reinterpret_cast<const i32x4*>(vS + (size_t)cc * 16 * 2048 + kv0 + 64);
        }

        {
            const bf16* Kc = &Kl[cur][0];
            const bf16* Vc = &Vt[cur][0];

            // S^T = K @ Q : p0 = kv rows 0..31 (+4*hi offsets), p1 = rows 32..63
            f32x16 p0 = {}, p1 = {};
#pragma unroll
            for (int s = 0; s < 4; ++s) {
                bf16x8 kf0 = *reinterpret_cast<const bf16x8*>(&Kc[q31 * LDK + s * 16 + hi * 8]);
                bf16x8 kf1 = *reinterpret_cast<const bf16x8*>(&Kc[(32 + q31) * LDK + s * 16 + hi * 8]);
                p0 = MFMA32(kf0, qf[s], p0);
                p1 = MFMA32(kf1, qf[s], p1);
            }

            // causal mask: p[r] has kv = kv0 + cr(r) + 4*hi, cr(r)=(r&3)+8*(r>>2)
            if (kv0 + 63 > q0w) {
                const int lim = qa - kv0 - 4 * hi;
#pragma unroll
                for (int r = 0; r < 16; ++r) {
                    const int cr = (r & 3) + 8 * (r >> 2);
                    if (cr > lim)      p0[r] = -1e30f;
                    if (cr + 32 > lim) p1[r] = -1e30f;
                }
            }

            // row max (lane owns one q-row; merge halves with one shfl)
            float rm = p0[0];
#pragma unroll
            for (int r = 1; r < 16; ++r) rm = fmaxf(rm, p0[r]);
#pragma unroll
            for (int r = 0; r < 16; ++r) rm = fmaxf(rm, p1[r]);
            rm = fmaxf(rm, __shfl_xor(rm, 32));

            // T13 defer-max: rescale only when max grew by >8 (exp2 domain)
            if (!__all(rm - m_run <= 8.0f)) {
                float mnew = fmaxf(m_run, rm);
                float alpha = exp2f(m_run - mnew);
                m_run = mnew;
                l_run *= alpha;
                if (hi == 0) wred[w][q31] = alpha;
#pragma unroll
                for (int g = 0; g < 4; ++g) {
                    f32x4 av = *reinterpret_cast<const f32x4*>(&wred[w][8 * g + 4 * hi]);
#pragma unroll
                    for (int tt = 0; tt < 4; ++tt) {
                        o0[4 * g + tt] *= av[tt];
                        o1[4 * g + tt] *= av[tt];
                    }
                }
            }

            // exp + row sum
            float rsum = 0.f;
#pragma unroll
            for (int r = 0; r < 16; ++r) { p0[r] = exp2f(p0[r] - m_run); rsum += p0[r]; }
#pragma unroll
            for (int r = 0; r < 16; ++r) { p1[r] = exp2f(p1[r] - m_run); rsum += p1[r]; }
            rsum += __shfl_xor(rsum, 32);
            l_run += rsum;

            // pack P to bf16 pairs per kv-octet
            unsigned A[8], Bv[8];
#pragma unroll
            for (int m = 0; m < 4; ++m) {
                A[m]      = pkbf16(p0[4 * m],     p0[4 * m + 1]);
                Bv[m]     = pkbf16(p0[4 * m + 2], p0[4 * m + 3]);
                A[m + 4]  = pkbf16(p1[4 * m],     p1[4 * m + 1]);
                Bv[m + 4] = pkbf16(p1[4 * m + 2], p1[4 * m + 3]);
            }

            // PV: pa[ks] covers kv = 16ks+8hi+0..7; missing half from partner lane (xor 32)
#pragma unroll
            for (int ks = 0; ks < 4; ++ks) {
                unsigned sa = hi ? A[2 * ks]  : A[2 * ks + 1];
                unsigned sb = hi ? Bv[2 * ks] : Bv[2 * ks + 1];
                unsigned ra = (unsigned)__shfl_xor((int)sa, 32);
                unsigned rb = (unsigned)__shfl_xor((int)sb, 32);
                union { unsigned u[4]; bf16x8 v; } pa;
                if (hi == 0) { pa.u[0] = A[2 * ks];  pa.u[1] = Bv[2 * ks];  pa.u[2] = ra; pa.u[3] = rb; }
                else         { pa.u[0] = ra; pa.u[1] = rb; pa.u[2] = A[2 * ks + 1]; pa.u[3] = Bv[2 * ks + 1]; }
                bf16x8 vf0 = *reinterpret_cast<const bf16x8*>(&Vc[q31 * LDV + ks * 16 + hi * 8]);
                bf16x8 vf1 = *reinterpret_cast<const bf16x8*>(&Vc[(32 + q31) * LDV + ks * 16 + hi * 8]);
                o0 = MFMA32(pa.v, vf0, o0);
                o1 = MFMA32(pa.v, vf1, o1);
            }
        }

        if (pf) {                                    // write next buffer, single barrier
            const int nxt = cur ^ 1;
            *reinterpret_cast<i32x4*>(&Kl[nxt][kr * LDK + kc])            = ka0;
            *reinterpret_cast<i32x4*>(&Kl[nxt][kr * LDK + kc + 8])        = ka1;
            *reinterpret_cast<i32x4*>(&Kl[nxt][(kr + 32) * LDK + kc])     = ka2;
            *reinterpret_cast<i32x4*>(&Kl[nxt][(kr + 32) * LDK + kc + 8]) = ka3;
#pragma unroll
            for (int cc = 0; cc < 4; ++cc)
                *reinterpret_cast<i32x4*>(&Vt[nxt][(vd + cc * 16) * LDV + vk8]) = vv[cc];
            __syncthreads();
            cur = nxt;
        }
    }

    // epilogue: O[q = q0w + cr(r)+4hi][d = q31 (+32)] * (1/l[q])
    if (hi == 0) wred[w][q31] = 1.0f / l_run;
#pragma unroll
    for (int g = 0; g < 4; ++g) {
        f32x4 iv = *reinterpret_cast<const f32x4*>(&wred[w][8 * g + 4 * hi]);
#pragma unroll
        for (int tt = 0; tt < 4; ++tt) {
            const int r = 4 * g + tt;
            const int qrow = q0w + 8 * g + 4 * hi + tt;
            bf16* op = outp + (size_t)(b * 2048 + qrow) * 1024 + h * 64 + q31;
            op[0]  = __float2bfloat16(o0[r] * iv[tt]);
            op[32] = __float2bfloat16(o1[r] * iv[tt]);
        }
    }
}

// ---------------------------------------------------------------- launch
extern "C" void kernel_launch(void* const* d_in, const int* in_sizes, int n_in,
                              void* d_out, int out_size, void* d_ws, size_t ws_size,
                              hipStream_t stream)
{
    const float* x      = (const float*)d_in[0];
    const float* qkv_w  = (const float*)d_in[1];
    const float* qkv_b  = (const float*)d_in[2];
    const float* proj_w = (const float*)d_in[3];
    const float* proj_b = (const float*)d_in[4];
    float* out = (float*)d_out;

    char* ws = (char*)d_ws;
    bf16* x_bf   = (bf16*)ws;  ws += (size_t)4096 * 1024 * 2;   // dead after QKV GEMM
    bf16* wq_bf  = (bf16*)ws;  ws += (size_t)3072 * 1024 * 2;
    bf16* wp_bf  = (bf16*)ws;  ws += (size_t)1024 * 1024 * 2;
    bf16* qkvbuf = (bf16*)ws;  ws += (size_t)4096 * 3072 * 2;
    bf16* aout   = (bf16*)ws;  ws += (size_t)4096 * 1024 * 2;
    float2* tab  = (float2*)ws;
    bf16* vt = x_bf;   // reuse x_bf's 8MB for V^T [32][64][2048] (exact fit)

    cvt_f32_bf16<<<4096, 256, 0, stream>>>(x, x_bf, 1048576);
    cvt_f32_bf16<<<3072, 256, 0, stream>>>(qkv_w, wq_bf, 786432);
    cvt_f32_bf16<<<1024, 256, 0, stream>>>(proj_w, wp_bf, 262144);
    rope_table_kernel<<<256, 256, 0, stream>>>(tab);

    // qkv = x @ qkv_w.T + qkv_b   [4096, 3072] bf16
    gemm_bt_kernel<bf16><<<dim3(32, 24), 256, 0, stream>>>(x_bf, wq_bf, qkv_b, qkvbuf, 4096, 3072, 1024);
    // RoPE in place on q,k sections
    rope_apply_kernel<<<4096, 256, 0, stream>>>(qkvbuf, tab);
    // V^T into vt (x_bf storage, now dead)
    transpose_v_kernel<<<1024, 256, 0, stream>>>(qkvbuf, vt);
    // causal flash attention -> aout [4096, 1024] bf16
    attn_kernel<<<dim3(32, 32), 128, 0, stream>>>(qkvbuf, vt, aout);
    // out = aout @ proj_w.T + proj_b  (fp32)
    gemm_bt_kernel<float><<<dim3(32, 8), 256, 0, stream>>>(aout, wp_bf, proj_b, out, 4096, 1024, 1024);
}